// Round 7
// baseline (240.557 us; speedup 1.0000x reference)
//
#include <hip/hip_runtime.h>

// Problem constants
#define B_  2
#define N_  2048
#define M_  2048
#define D_  1024
#define H_  16
#define DH_ 64

typedef __bf16 bf16x8 __attribute__((ext_vector_type(8)));
typedef __bf16 bf16x4 __attribute__((ext_vector_type(4)));
typedef short  short4v __attribute__((ext_vector_type(4)));
typedef float  f32x4  __attribute__((ext_vector_type(4)));

#define GAS(p) ((__attribute__((address_space(1))) void*)(p))
#define LAS(p) ((__attribute__((address_space(3))) void*)(p))

// SCALE * log2(e), folded into Q at projection time
#define QPRESCALE 0.18033688011112042f

__device__ __forceinline__ unsigned short f2bf(float f) {
    unsigned int u = __builtin_bit_cast(unsigned int, f);
    u += 0x7fffu + ((u >> 16) & 1u);   // round-to-nearest-even
    return (unsigned short)(u >> 16);
}

// ------- kernel 1: prep = weight transpose+cast (z<4) | input cast (z==4) -------
__global__ __launch_bounds__(256) void prep(
    const float* __restrict__ x, const float* __restrict__ ctx,
    const float* __restrict__ Wq, const float* __restrict__ Wk,
    const float* __restrict__ Wv, const float* __restrict__ Wo,
    unsigned short* __restrict__ xb, unsigned short* __restrict__ cb,
    unsigned short* __restrict__ WTbase)
{
    if (blockIdx.z == 4) {
        int blk = blockIdx.y * 32 + blockIdx.x;
        int stride = 1024 * 256;
        for (int i = blk * 256 + threadIdx.x; i < 2097152; i += stride) {
            const float4* src; unsigned short* dst; int j;
            if (i < 1048576) { src = (const float4*)x;   dst = xb; j = i; }
            else             { src = (const float4*)ctx; dst = cb; j = i - 1048576; }
            float4 v = src[j];
            ushort4 o = make_ushort4(f2bf(v.x), f2bf(v.y), f2bf(v.z), f2bf(v.w));
            *(ushort4*)(dst + 4*j) = o;
        }
        return;
    }
    const float* W = (blockIdx.z == 0) ? Wq : (blockIdx.z == 1) ? Wk
                    : (blockIdx.z == 2) ? Wv : Wo;
    unsigned short* WT = WTbase + (size_t)blockIdx.z * 1048576;
    __shared__ unsigned short t[32][33];
    int tx = threadIdx.x & 31, ty8 = threadIdx.x >> 5;   // 32 x 8
    int c = blockIdx.x * 32 + tx;
#pragma unroll
    for (int i = 0; i < 4; ++i) {
        int r = blockIdx.y * 32 + i*8 + ty8;
        t[i*8 + ty8][tx] = f2bf(W[(size_t)r * 1024 + c]);
    }
    __syncthreads();
    int c2 = blockIdx.y * 32 + tx;
#pragma unroll
    for (int i = 0; i < 4; ++i) {
        int r2 = blockIdx.x * 32 + i*8 + ty8;
        WT[(size_t)r2 * 1024 + c2] = t[tx][i*8 + ty8];
    }
}

// ---------------- kernel 2/4: 128x128 bf16 GEMM, C = A * Bt^T ----------------
// mode 0: A=xb  -> Q*QPRESCALE stored [B,H,N,64] (bf16)
// mode 1: A=cb  -> K   stored [B,H,M,64]   (bf16)
// mode 2: A=cb  -> V^T stored [B,H,64,M]   (bf16)
// mode 3: A=ao  -> out fp32 [B,N,1024] + bias
__global__ __launch_bounds__(256) void gemm128(
    const unsigned short* __restrict__ xb,
    const unsigned short* __restrict__ cb,
    const unsigned short* __restrict__ wT,
    const unsigned short* __restrict__ aoA,
    unsigned short* __restrict__ qkv_out,
    const float* __restrict__ bo,
    float* __restrict__ outF,
    int base_mode)
{
    __shared__ __align__(16) unsigned short As[128*32];
    __shared__ __align__(16) unsigned short Bs[128*32];

    const int mode = base_mode + blockIdx.z;
    const unsigned short* Amat = (mode == 0) ? xb : (mode == 3) ? aoA : cb;
    const unsigned short* Bt = wT + (size_t)mode * 1048576;

    const int tid = threadIdx.x;
    const int w = tid >> 6, l = tid & 63;
    const int quad = l >> 4, l16 = l & 15;
    const int wm = w & 1, wn = w >> 1;
    const int row0 = blockIdx.y * 128, col0 = blockIdx.x * 128;

    f32x4 acc[4][4];
#pragma unroll
    for (int i = 0; i < 4; ++i)
#pragma unroll
        for (int j = 0; j < 4; ++j) acc[i][j] = (f32x4){0.f, 0.f, 0.f, 0.f};

    for (int k0 = 0; k0 < 1024; k0 += 32) {
        __syncthreads();
#pragma unroll
        for (int i = 0; i < 2; ++i) {
            int s = i*256 + w*64 + l;
            int m = s >> 2, c = s & 3;
            int cs = c ^ ((m >> 1) & 3);
            __builtin_amdgcn_global_load_lds(
                GAS(Amat + (size_t)(row0 + m)*1024 + k0 + cs*8),
                LAS(As + (i*256 + w*64)*8), 16, 0, 0);
            __builtin_amdgcn_global_load_lds(
                GAS(Bt + (size_t)(col0 + m)*1024 + k0 + cs*8),
                LAS(Bs + (i*256 + w*64)*8), 16, 0, 0);
        }
        __syncthreads();

        bf16x8 af[4], bfr[4];
#pragma unroll
        for (int mt = 0; mt < 4; ++mt) {
            int m = wm*64 + mt*16 + l16;
            af[mt] = *reinterpret_cast<const bf16x8*>(As + m*32 + (quad ^ ((m >> 1) & 3))*8);
            int n = wn*64 + mt*16 + l16;
            bfr[mt] = *reinterpret_cast<const bf16x8*>(Bs + n*32 + (quad ^ ((n >> 1) & 3))*8);
        }
#pragma unroll
        for (int mt = 0; mt < 4; ++mt)
#pragma unroll
            for (int nt = 0; nt < 4; ++nt)
                acc[mt][nt] = __builtin_amdgcn_mfma_f32_16x16x32_bf16(
                    af[mt], bfr[nt], acc[mt][nt], 0, 0, 0);
    }

    if (mode == 3) {
#pragma unroll
        for (int nt = 0; nt < 4; ++nt) {
            int col = col0 + wn*64 + nt*16 + l16;
            float bv = bo[col];
#pragma unroll
            for (int mt = 0; mt < 4; ++mt) {
                int gr = row0 + wm*64 + mt*16 + quad*4;
#pragma unroll
                for (int r = 0; r < 4; ++r)
                    outF[(size_t)(gr + r)*1024 + col] = acc[mt][nt][r] + bv;
            }
        }
    } else if (mode == 2) {
        // V^T: [B,H,64,M]
#pragma unroll
        for (int mt = 0; mt < 4; ++mt) {
            int gr = row0 + wm*64 + mt*16 + quad*4;
            int b = gr >> 11, nidx = gr & 2047;
#pragma unroll
            for (int nt = 0; nt < 4; ++nt) {
                int col = col0 + wn*64 + nt*16 + l16;
                int h = col >> 6, d = col & 63;
                ushort4 pk = make_ushort4(f2bf(acc[mt][nt][0]), f2bf(acc[mt][nt][1]),
                                          f2bf(acc[mt][nt][2]), f2bf(acc[mt][nt][3]));
                *(ushort4*)(qkv_out + (size_t)2*4194304
                            + (size_t)((b*16 + h)*64 + d)*2048 + nidx) = pk;
            }
        }
    } else {
        // Q/K: [B,H,seq,64]; Q is pre-scaled by SCALE*log2(e)
        const float qs = (mode == 0) ? QPRESCALE : 1.0f;
#pragma unroll
        for (int mt = 0; mt < 4; ++mt) {
            int gr = row0 + wm*64 + mt*16 + quad*4;
#pragma unroll
            for (int nt = 0; nt < 4; ++nt) {
                int col = col0 + wn*64 + nt*16 + l16;
                int h = col >> 6, d = col & 63;
#pragma unroll
                for (int r = 0; r < 4; ++r) {
                    int grr = gr + r;
                    int b = grr >> 11, nidx = grr & 2047;
                    qkv_out[(size_t)mode*4194304
                            + (size_t)((b*16 + h)*2048 + nidx)*64 + d]
                        = f2bf(acc[mt][nt][r] * qs);
                }
            }
        }
    }
}

// ---------------- kernel 3: flash attention (K-direct, V-only LDS) ----------------
// q-tile 128 (4 waves x 32 q), KV-tile 64.  Round-6 lesson: with K+V both in
// LDS the per-CU LDS pipe is the bottleneck (every wave re-reads the full
// tile).  Here K-fragments are loaded global->register (coalesced dwordx4;
// all 4 waves read identical addresses -> L1-served) with a 1-iteration
// register prefetch; LDS holds only V (2 x 9 KB double-buffered).
// S^T = K Q^T (C-layout == 16x16x16 B-frag layout) -> P^T feeds O^T = V^T P^T
// straight from registers.  Shift-free softmax (Q carries SCALE*log2e);
// denominator = per-lane fp32 partials, 2 shuffles at the end.
__global__ __launch_bounds__(256, 2) void flash_attn(
    const unsigned short* __restrict__ qw,   // [B,H,N,64]  (pre-scaled)
    const unsigned short* __restrict__ kw,   // [B,H,M,64]
    const unsigned short* __restrict__ vtw,  // [B,H,64,M]
    unsigned short* __restrict__ ao)         // [B,N,H*64]
{
    // V tile: 64 d-rows x (64 data + 8 pad) ushorts = 144B rows, 9 chunks/row
    __shared__ __align__(16) unsigned short Vt[2][4608];   // 2 x 9216 B

    const int tid = threadIdx.x;
    const int w = tid >> 6, l = tid & 63;
    const int quad = l >> 4, l16 = l & 15;
    const int bh = blockIdx.z * H_ + blockIdx.y;
    const int q0 = blockIdx.x * 128 + w * 32;   // this wave's 32 queries

    // V staging: 576 slots (64 rows x 9 chunks); rounds 0,1 full, round 2 = wave 0
    int goff[3];
#pragma unroll
    for (int i = 0; i < 3; ++i) {
        int n = i*256 + w*64 + l;
        int row = n / 9, c = n % 9;  if (c > 7) c = 7;     // clamp pad chunk
        goff[i] = row*2048 + c*8;                          // V^T row stride 2048
    }
    const unsigned short* kbase = kw + (size_t)bh*131072;
    const unsigned short* vbase = vtw + (size_t)bh*131072;

    // Q as B-frag (K=32): B[n=q][k=d]; two 16-q groups
    bf16x8 qf[2][2];
#pragma unroll
    for (int qg = 0; qg < 2; ++qg)
#pragma unroll
        for (int s = 0; s < 2; ++s)
            qf[qg][s] = *reinterpret_cast<const bf16x8*>(
                qw + (size_t)(bh*2048 + q0 + qg*16 + l16)*64 + s*32 + quad*8);

    f32x4 accO[2][4];
#pragma unroll
    for (int qg = 0; qg < 2; ++qg)
#pragma unroll
        for (int td = 0; td < 4; ++td) accO[qg][td] = (f32x4){0.f, 0.f, 0.f, 0.f};
    float lpart[2] = {0.f, 0.f};

    const f32x4 zz = (f32x4){0.f, 0.f, 0.f, 0.f};

    // K-frag register double-buffer: [t*2+s], frag = A[m=kv=l16][k=quad*8+j]
    const int kfo = l16*64 + quad*8;    // within-tile ushort offset
    bf16x8 ka[8], kb[8];

    // preload: V tile 0 -> buf 0; K frags iter 0 -> ka
    {
#pragma unroll
        for (int i = 0; i < 2; ++i)
            __builtin_amdgcn_global_load_lds(GAS(vbase + goff[i]),
                LAS(&Vt[0][(i*256 + w*64)*8]), 16, 0, 0);
        if (w == 0)
            __builtin_amdgcn_global_load_lds(GAS(vbase + goff[2]),
                LAS(&Vt[0][512*8]), 16, 0, 0);
#pragma unroll
        for (int t = 0; t < 4; ++t)
#pragma unroll
            for (int s = 0; s < 2; ++s)
                ka[t*2+s] = *reinterpret_cast<const bf16x8*>(
                    kbase + t*1024 + s*32 + kfo);
    }

#pragma unroll 2
    for (int it = 0; it < 32; ++it) {
        const int cur = it & 1;
        bf16x8* KU = (it & 1) ? kb : ka;    // frags for this iter (loaded last iter)
        bf16x8* KP = (it & 1) ? ka : kb;    // prefetch target for next iter

        __syncthreads();   // V[cur] staged; all waves done reading V[cur^1]

        // stage V(it+1) into the other buffer (after barrier -> stays in flight)
        if (it + 1 < 32) {
            const unsigned short* vp = vbase + (it+1)*64;
#pragma unroll
            for (int i = 0; i < 2; ++i)
                __builtin_amdgcn_global_load_lds(GAS(vp + goff[i]),
                    LAS(&Vt[cur^1][(i*256 + w*64)*8]), 16, 0, 0);
            if (w == 0)
                __builtin_amdgcn_global_load_lds(GAS(vp + goff[2]),
                    LAS(&Vt[cur^1][512*8]), 16, 0, 0);
        }

        // S^T = K Q^T : A = K-frag (registers), B = Q-frag; zero-C first MFMA
        f32x4 sac[2][4];
#pragma unroll
        for (int t = 0; t < 4; ++t) {
            sac[0][t] = __builtin_amdgcn_mfma_f32_16x16x32_bf16(KU[t*2+0], qf[0][0], zz, 0, 0, 0);
            sac[1][t] = __builtin_amdgcn_mfma_f32_16x16x32_bf16(KU[t*2+0], qf[1][0], zz, 0, 0, 0);
            sac[0][t] = __builtin_amdgcn_mfma_f32_16x16x32_bf16(KU[t*2+1], qf[0][1], sac[0][t], 0, 0, 0);
            sac[1][t] = __builtin_amdgcn_mfma_f32_16x16x32_bf16(KU[t*2+1], qf[1][1], sac[1][t], 0, 0, 0);
        }

        // prefetch K frags for it+1 (wraps harmlessly at the end)
        {
            const unsigned short* kp = kbase + (((it+1) & 31))*4096;
#pragma unroll
            for (int t = 0; t < 4; ++t)
#pragma unroll
                for (int s = 0; s < 2; ++s)
                    KP[t*2+s] = *reinterpret_cast<const bf16x8*>(
                        kp + t*1024 + s*32 + kfo);
        }

        // P^T = exp2(S^T) (raw v_exp_f32); per-lane fp32 partial row-sums
        short4v pk[2][4];
#pragma unroll
        for (int qg = 0; qg < 2; ++qg) {
            float s0 = 0.f, s1 = 0.f, s2 = 0.f, s3 = 0.f;
#pragma unroll
            for (int t = 0; t < 4; ++t) {
                float p0 = __builtin_amdgcn_exp2f(sac[qg][t][0]);
                float p1 = __builtin_amdgcn_exp2f(sac[qg][t][1]);
                float p2 = __builtin_amdgcn_exp2f(sac[qg][t][2]);
                float p3 = __builtin_amdgcn_exp2f(sac[qg][t][3]);
                s0 += p0; s1 += p1; s2 += p2; s3 += p3;
                bf16x4 pb;
                pb[0] = (__bf16)p0; pb[1] = (__bf16)p1;
                pb[2] = (__bf16)p2; pb[3] = (__bf16)p3;
                pk[qg][t] = __builtin_bit_cast(short4v, pb);
            }
            lpart[qg] += (s0 + s1) + (s2 + s3);
        }

        // O^T += V^T P^T : A = V^T-frag (m=d, k=kv) from LDS, B = P^T (registers)
#pragma unroll
        for (int td = 0; td < 4; ++td) {
            const unsigned short* vrow = &Vt[cur][(td*16 + l16)*72 + quad*4];
#pragma unroll
            for (int t = 0; t < 4; ++t) {
                short4v vf = *reinterpret_cast<const short4v*>(vrow + t*16);
                accO[0][td] = __builtin_amdgcn_mfma_f32_16x16x16bf16_1k(
                    vf, pk[0][t], accO[0][td], 0, 0, 0);
                accO[1][td] = __builtin_amdgcn_mfma_f32_16x16x16bf16_1k(
                    vf, pk[1][t], accO[1][td], 0, 0, 0);
            }
        }
    }

    // epilogue: reduce denominator across quads (kv partials), normalize, store
#pragma unroll
    for (int qg = 0; qg < 2; ++qg) {
        float s = lpart[qg];
        s += __shfl_xor(s, 16);
        s += __shfl_xor(s, 32);
        float inv = 1.f / s;
        const size_t rowbase =
            (size_t)(blockIdx.z*2048 + q0 + qg*16 + l16)*1024 + blockIdx.y*64;
#pragma unroll
        for (int td = 0; td < 4; ++td)
#pragma unroll
            for (int r = 0; r < 4; ++r)
                ao[rowbase + td*16 + quad*4 + r] = f2bf(accO[qg][td][r] * inv);
    }
}

extern "C" void kernel_launch(void* const* d_in, const int* in_sizes, int n_in,
                              void* d_out, int out_size, void* d_ws, size_t ws_size,
                              hipStream_t stream)
{
    const float* x   = (const float*)d_in[0];
    const float* ctx = (const float*)d_in[1];
    const float* Wq  = (const float*)d_in[2];
    const float* Wk  = (const float*)d_in[3];
    const float* Wv  = (const float*)d_in[4];
    const float* Wo  = (const float*)d_in[5];
    const float* bo  = (const float*)d_in[6];
    float* out = (float*)d_out;

    unsigned short* ws  = (unsigned short*)d_ws;
    unsigned short* xb  = ws;
    unsigned short* cb  = ws + 4194304;
    unsigned short* wT  = ws + 8388608;
    unsigned short* qkv = ws + 12582912;
    unsigned short* ao  = ws;  // reuse xb space (xb dead after projections)

    prep<<<dim3(32, 32, 5), dim3(256), 0, stream>>>(x, ctx, Wq, Wk, Wv, Wo, xb, cb, wT);
    gemm128<<<dim3(8, 32, 3), dim3(256), 0, stream>>>(xb, cb, wT, ao, qkv, bo, out, 0);
    flash_attn<<<dim3(16, 16, 2), dim3(256), 0, stream>>>(qkv, qkv + 4194304, qkv + 8388608, ao);
    gemm128<<<dim3(8, 32, 1), dim3(256), 0, stream>>>(xb, cb, wT, ao, qkv, bo, out, 3);
}

// Round 8
// 205.328 us; speedup vs baseline: 1.1716x; 1.1716x over previous
//
#include <hip/hip_runtime.h>

// Problem constants
#define B_  2
#define N_  2048
#define M_  2048
#define D_  1024
#define H_  16
#define DH_ 64

typedef __bf16 bf16x8 __attribute__((ext_vector_type(8)));
typedef __bf16 bf16x4 __attribute__((ext_vector_type(4)));
typedef short  short4v __attribute__((ext_vector_type(4)));
typedef float  f32x4  __attribute__((ext_vector_type(4)));

#define GAS(p) ((__attribute__((address_space(1))) void*)(p))
#define LAS(p) ((__attribute__((address_space(3))) void*)(p))

// SCALE * log2(e), folded into Q at projection time
#define QPRESCALE 0.18033688011112042f

__device__ __forceinline__ unsigned short f2bf(float f) {
    unsigned int u = __builtin_bit_cast(unsigned int, f);
    u += 0x7fffu + ((u >> 16) & 1u);   // round-to-nearest-even
    return (unsigned short)(u >> 16);
}

// ------- kernel 1: prep = weight transpose+cast (z<4) | input cast (z==4) -------
__global__ __launch_bounds__(256) void prep(
    const float* __restrict__ x, const float* __restrict__ ctx,
    const float* __restrict__ Wq, const float* __restrict__ Wk,
    const float* __restrict__ Wv, const float* __restrict__ Wo,
    unsigned short* __restrict__ xb, unsigned short* __restrict__ cb,
    unsigned short* __restrict__ WTbase)
{
    if (blockIdx.z == 4) {
        int blk = blockIdx.y * 32 + blockIdx.x;
        int stride = 1024 * 256;
        for (int i = blk * 256 + threadIdx.x; i < 2097152; i += stride) {
            const float4* src; unsigned short* dst; int j;
            if (i < 1048576) { src = (const float4*)x;   dst = xb; j = i; }
            else             { src = (const float4*)ctx; dst = cb; j = i - 1048576; }
            float4 v = src[j];
            ushort4 o = make_ushort4(f2bf(v.x), f2bf(v.y), f2bf(v.z), f2bf(v.w));
            *(ushort4*)(dst + 4*j) = o;
        }
        return;
    }
    const float* W = (blockIdx.z == 0) ? Wq : (blockIdx.z == 1) ? Wk
                    : (blockIdx.z == 2) ? Wv : Wo;
    unsigned short* WT = WTbase + (size_t)blockIdx.z * 1048576;
    __shared__ unsigned short t[32][33];
    int tx = threadIdx.x & 31, ty8 = threadIdx.x >> 5;   // 32 x 8
    int c = blockIdx.x * 32 + tx;
#pragma unroll
    for (int i = 0; i < 4; ++i) {
        int r = blockIdx.y * 32 + i*8 + ty8;
        t[i*8 + ty8][tx] = f2bf(W[(size_t)r * 1024 + c]);
    }
    __syncthreads();
    int c2 = blockIdx.y * 32 + tx;
#pragma unroll
    for (int i = 0; i < 4; ++i) {
        int r2 = blockIdx.x * 32 + i*8 + ty8;
        WT[(size_t)r2 * 1024 + c2] = t[tx][i*8 + ty8];
    }
}

// ---------------- kernel 2/4: 128x128 bf16 GEMM, C = A * Bt^T ----------------
// OPERAND-SWAPPED for modes 0/1/3 so the MFMA C-layout r-direction (row =
// quad*4+r) runs along the OUTPUT-CHANNEL: the 4 acc regs become one
// vectorized store (round-7 fix for the 64-scattered-2B-stores epilogue).
// mode 0: A=WqT, Bt=xb  -> Q^T tile, stored [B,H,N,64] bf16 (*QPRESCALE), ushort4
// mode 1: A=WkT, Bt=cb  -> K^T tile, stored [B,H,M,64] bf16, ushort4
// mode 2: A=cb,  Bt=WvT -> V^T stored [B,H,64,M] bf16, ushort4 (original swap)
// mode 3: A=WoT, Bt=ao  -> out^T tile, stored fp32 [B,N,1024] + bias, float4
__global__ __launch_bounds__(256) void gemm128(
    const unsigned short* __restrict__ xb,
    const unsigned short* __restrict__ cb,
    const unsigned short* __restrict__ wT,
    const unsigned short* __restrict__ aoA,
    unsigned short* __restrict__ qkv_out,
    const float* __restrict__ bo,
    float* __restrict__ outF,
    int base_mode)
{
    __shared__ __align__(16) unsigned short As[128*32];
    __shared__ __align__(16) unsigned short Bs[128*32];

    const int mode = base_mode + blockIdx.z;
    const unsigned short* Amat;
    const unsigned short* Bt;
    if (mode == 0)      { Amat = wT;               Bt = xb; }
    else if (mode == 1) { Amat = wT + 1048576;     Bt = cb; }
    else if (mode == 2) { Amat = cb;               Bt = wT + 2*1048576; }
    else                { Amat = wT + 3*1048576;   Bt = aoA; }

    const int tid = threadIdx.x;
    const int w = tid >> 6, l = tid & 63;
    const int quad = l >> 4, l16 = l & 15;
    const int wm = w & 1, wn = w >> 1;
    // swapped modes: rows = 1024 (y:8), cols = 4096 (x:32); mode 2 reversed
    int row0, col0;
    if (mode == 2) { row0 = blockIdx.x * 128; col0 = blockIdx.y * 128; }
    else           { row0 = blockIdx.y * 128; col0 = blockIdx.x * 128; }

    f32x4 acc[4][4];
#pragma unroll
    for (int i = 0; i < 4; ++i)
#pragma unroll
        for (int j = 0; j < 4; ++j) acc[i][j] = (f32x4){0.f, 0.f, 0.f, 0.f};

    for (int k0 = 0; k0 < 1024; k0 += 32) {
        __syncthreads();
#pragma unroll
        for (int i = 0; i < 2; ++i) {
            int s = i*256 + w*64 + l;
            int m = s >> 2, c = s & 3;
            int cs = c ^ ((m >> 1) & 3);
            __builtin_amdgcn_global_load_lds(
                GAS(Amat + (size_t)(row0 + m)*1024 + k0 + cs*8),
                LAS(As + (i*256 + w*64)*8), 16, 0, 0);
            __builtin_amdgcn_global_load_lds(
                GAS(Bt + (size_t)(col0 + m)*1024 + k0 + cs*8),
                LAS(Bs + (i*256 + w*64)*8), 16, 0, 0);
        }
        __syncthreads();

        bf16x8 af[4], bfr[4];
#pragma unroll
        for (int mt = 0; mt < 4; ++mt) {
            int m = wm*64 + mt*16 + l16;
            af[mt] = *reinterpret_cast<const bf16x8*>(As + m*32 + (quad ^ ((m >> 1) & 3))*8);
            int n = wn*64 + mt*16 + l16;
            bfr[mt] = *reinterpret_cast<const bf16x8*>(Bs + n*32 + (quad ^ ((n >> 1) & 3))*8);
        }
#pragma unroll
        for (int mt = 0; mt < 4; ++mt)
#pragma unroll
            for (int nt = 0; nt < 4; ++nt)
                acc[mt][nt] = __builtin_amdgcn_mfma_f32_16x16x32_bf16(
                    af[mt], bfr[nt], acc[mt][nt], 0, 0, 0);
    }

    // Epilogues.  C/D layout: col = l16, row = quad*4 + r  [m89/m91 verified]
    if (mode == 3) {
        // out^T tile: row = out-channel c (4 consecutive per lane), col = token n
#pragma unroll
        for (int mt = 0; mt < 4; ++mt) {
            int c = row0 + wm*64 + mt*16 + quad*4;
            float4 bv = *(const float4*)(bo + c);
#pragma unroll
            for (int nt = 0; nt < 4; ++nt) {
                int n = col0 + wn*64 + nt*16 + l16;
                float4 ov = make_float4(acc[mt][nt][0] + bv.x, acc[mt][nt][1] + bv.y,
                                        acc[mt][nt][2] + bv.z, acc[mt][nt][3] + bv.w);
                *(float4*)(outF + (size_t)n*1024 + c) = ov;
            }
        }
    } else if (mode == 2) {
        // V^T: [B,H,64,M]; r-direction = token n -> ushort4
#pragma unroll
        for (int mt = 0; mt < 4; ++mt) {
            int gr = row0 + wm*64 + mt*16 + quad*4;
            int b = gr >> 11, nidx = gr & 2047;
#pragma unroll
            for (int nt = 0; nt < 4; ++nt) {
                int col = col0 + wn*64 + nt*16 + l16;
                int h = col >> 6, d = col & 63;
                ushort4 pk = make_ushort4(f2bf(acc[mt][nt][0]), f2bf(acc[mt][nt][1]),
                                          f2bf(acc[mt][nt][2]), f2bf(acc[mt][nt][3]));
                *(ushort4*)(qkv_out + (size_t)2*4194304
                            + (size_t)((b*16 + h)*64 + d)*2048 + nidx) = pk;
            }
        }
    } else {
        // Q^T/K^T tile: row = channel c=(h,d) (4 consecutive d), col = token n
        const float qs = (mode == 0) ? QPRESCALE : 1.0f;
        unsigned short* obase = qkv_out + (size_t)mode*4194304;
#pragma unroll
        for (int nt = 0; nt < 4; ++nt) {
            int n = col0 + wn*64 + nt*16 + l16;
            int b = n >> 11, nidx = n & 2047;
#pragma unroll
            for (int mt = 0; mt < 4; ++mt) {
                int c = row0 + wm*64 + mt*16 + quad*4;
                int h = c >> 6, d = c & 63;
                ushort4 pkv = make_ushort4(
                    f2bf(acc[mt][nt][0] * qs), f2bf(acc[mt][nt][1] * qs),
                    f2bf(acc[mt][nt][2] * qs), f2bf(acc[mt][nt][3] * qs));
                *(ushort4*)(obase + (size_t)((b*16 + h)*2048 + nidx)*64 + d) = pkv;
            }
        }
    }
}

// ---------------- kernel 3: flash attention (round-5 version, verbatim) --------
// q-tile 128 (4 waves x 32 q), KV-tile 64, LDS double-buffered.
// Unified K|V slot space per tile:
//   slots [0,576)   = K  64 rows x 9 chunks (72-ushort rows, 8-ushort pad)
//   slots [576,1152)= V^T 64 rows x 9 chunks (72-ushort rows)
// Shift-free softmax (Q carries SCALE*log2e); denominator = per-lane fp32
// partial sums, 2 shuffles at the end.
__global__ __launch_bounds__(256, 2) void flash_attn(
    const unsigned short* __restrict__ qw,   // [B,H,N,64]  (pre-scaled)
    const unsigned short* __restrict__ kw,   // [B,H,M,64]
    const unsigned short* __restrict__ vtw,  // [B,H,64,M]
    unsigned short* __restrict__ ao)         // [B,N,H*64]
{
    __shared__ __align__(16) unsigned short Tile[2][9216];  // 2 x 18432 B

    const int tid = threadIdx.x;
    const int w = tid >> 6, l = tid & 63;
    const int quad = l >> 4, l16 = l & 15;
    const int bh = blockIdx.z * H_ + blockIdx.y;
    const int q0 = blockIdx.x * 128 + w * 32;   // this wave's 32 queries

    int goff[5];
#pragma unroll
    for (int i = 0; i < 5; ++i) {
        int n = i*256 + w*64 + l;
        int m = (n < 576) ? n : n - 576;
        int row = m / 9, c = m % 9;  if (c > 7) c = 7;     // clamp pad chunk
        goff[i] = (n < 576) ? row*64 + c*8 : row*2048 + c*8;
    }
    const unsigned short* kbase = kw + (size_t)bh*131072;
    const unsigned short* vbase = vtw + (size_t)bh*131072;

    // Q as B-frag (K=32): B[n=q][k=d]; two 16-q groups
    bf16x8 qf[2][2];
#pragma unroll
    for (int qg = 0; qg < 2; ++qg)
#pragma unroll
        for (int s = 0; s < 2; ++s)
            qf[qg][s] = *reinterpret_cast<const bf16x8*>(
                qw + (size_t)(bh*2048 + q0 + qg*16 + l16)*64 + s*32 + quad*8);

    f32x4 accO[2][4];
#pragma unroll
    for (int qg = 0; qg < 2; ++qg)
#pragma unroll
        for (int td = 0; td < 4; ++td) accO[qg][td] = (f32x4){0.f, 0.f, 0.f, 0.f};
    float lpart[2] = {0.f, 0.f};

    const f32x4 zz = (f32x4){0.f, 0.f, 0.f, 0.f};

    // ---- preload tile 0 into buf 0
    {
#pragma unroll
        for (int i = 0; i < 4; ++i) {
            const unsigned short* bp = (i*4 + w < 9) ? kbase : vbase;
            __builtin_amdgcn_global_load_lds(GAS(bp + goff[i]),
                LAS(&Tile[0][(i*256 + w*64)*8]), 16, 0, 0);
        }
        if (w < 2)
            __builtin_amdgcn_global_load_lds(GAS(vbase + goff[4]),
                LAS(&Tile[0][(1024 + w*64)*8]), 16, 0, 0);
    }

    for (int it = 0; it < 32; ++it) {
        __syncthreads();   // drains vmcnt -> Tile[it&1] ready
        const int cur = it & 1;

        if (it + 1 < 32) {
            const unsigned short* kp = kbase + (it+1)*4096;
            const unsigned short* vp = vbase + (it+1)*64;
#pragma unroll
            for (int i = 0; i < 4; ++i) {
                const unsigned short* bp = (i*4 + w < 9) ? kp : vp;
                __builtin_amdgcn_global_load_lds(GAS(bp + goff[i]),
                    LAS(&Tile[cur^1][(i*256 + w*64)*8]), 16, 0, 0);
            }
            if (w < 2)
                __builtin_amdgcn_global_load_lds(GAS(vp + goff[4]),
                    LAS(&Tile[cur^1][(1024 + w*64)*8]), 16, 0, 0);
        }

        const unsigned short* Ks = &Tile[cur][0];
        const unsigned short* Vs = &Tile[cur][4608];

        // S^T = K Q^T : A = K-frag (m=kv), B = Q-frag (n=q); zero-C first MFMA
        f32x4 sac[2][4];
#pragma unroll
        for (int t = 0; t < 4; ++t) {
            const unsigned short* krow = Ks + (t*16 + l16)*72 + quad*8;
            bf16x8 kf0 = *reinterpret_cast<const bf16x8*>(krow);
            bf16x8 kf1 = *reinterpret_cast<const bf16x8*>(krow + 32);
            sac[0][t] = __builtin_amdgcn_mfma_f32_16x16x32_bf16(kf0, qf[0][0], zz, 0, 0, 0);
            sac[1][t] = __builtin_amdgcn_mfma_f32_16x16x32_bf16(kf0, qf[1][0], zz, 0, 0, 0);
            sac[0][t] = __builtin_amdgcn_mfma_f32_16x16x32_bf16(kf1, qf[0][1], sac[0][t], 0, 0, 0);
            sac[1][t] = __builtin_amdgcn_mfma_f32_16x16x32_bf16(kf1, qf[1][1], sac[1][t], 0, 0, 0);
        }

        // P^T = exp2(S^T) (raw v_exp_f32); per-lane fp32 partial row-sums
        short4v pk[2][4];
#pragma unroll
        for (int qg = 0; qg < 2; ++qg) {
            float s0 = 0.f, s1 = 0.f, s2 = 0.f, s3 = 0.f;
#pragma unroll
            for (int t = 0; t < 4; ++t) {
                float p0 = __builtin_amdgcn_exp2f(sac[qg][t][0]);
                float p1 = __builtin_amdgcn_exp2f(sac[qg][t][1]);
                float p2 = __builtin_amdgcn_exp2f(sac[qg][t][2]);
                float p3 = __builtin_amdgcn_exp2f(sac[qg][t][3]);
                s0 += p0; s1 += p1; s2 += p2; s3 += p3;
                bf16x4 pb;
                pb[0] = (__bf16)p0; pb[1] = (__bf16)p1;
                pb[2] = (__bf16)p2; pb[3] = (__bf16)p3;
                pk[qg][t] = __builtin_bit_cast(short4v, pb);
            }
            lpart[qg] += (s0 + s1) + (s2 + s3);
        }

        // O^T += V^T P^T : A = V^T-frag (m=d, k=kv), B = P^T (registers)
#pragma unroll
        for (int td = 0; td < 4; ++td) {
            const unsigned short* vrow = Vs + (td*16 + l16)*72 + quad*4;
#pragma unroll
            for (int t = 0; t < 4; ++t) {
                short4v vf = *reinterpret_cast<const short4v*>(vrow + t*16);
                accO[0][td] = __builtin_amdgcn_mfma_f32_16x16x16bf16_1k(
                    vf, pk[0][t], accO[0][td], 0, 0, 0);
                accO[1][td] = __builtin_amdgcn_mfma_f32_16x16x16bf16_1k(
                    vf, pk[1][t], accO[1][td], 0, 0, 0);
            }
        }
    }

    // epilogue: reduce denominator across quads (kv partials), normalize, store
#pragma unroll
    for (int qg = 0; qg < 2; ++qg) {
        float s = lpart[qg];
        s += __shfl_xor(s, 16);
        s += __shfl_xor(s, 32);
        float inv = 1.f / s;
        const size_t rowbase =
            (size_t)(blockIdx.z*2048 + q0 + qg*16 + l16)*1024 + blockIdx.y*64;
#pragma unroll
        for (int td = 0; td < 4; ++td)
#pragma unroll
            for (int r = 0; r < 4; ++r)
                ao[rowbase + td*16 + quad*4 + r] = f2bf(accO[qg][td][r] * inv);
    }
}

extern "C" void kernel_launch(void* const* d_in, const int* in_sizes, int n_in,
                              void* d_out, int out_size, void* d_ws, size_t ws_size,
                              hipStream_t stream)
{
    const float* x   = (const float*)d_in[0];
    const float* ctx = (const float*)d_in[1];
    const float* Wq  = (const float*)d_in[2];
    const float* Wk  = (const float*)d_in[3];
    const float* Wv  = (const float*)d_in[4];
    const float* Wo  = (const float*)d_in[5];
    const float* bo  = (const float*)d_in[6];
    float* out = (float*)d_out;

    unsigned short* ws  = (unsigned short*)d_ws;
    unsigned short* xb  = ws;
    unsigned short* cb  = ws + 4194304;
    unsigned short* wT  = ws + 8388608;
    unsigned short* qkv = ws + 12582912;
    unsigned short* ao  = ws;  // reuse xb space (xb dead after projections)

    prep<<<dim3(32, 32, 5), dim3(256), 0, stream>>>(x, ctx, Wq, Wk, Wv, Wo, xb, cb, wT);
    gemm128<<<dim3(32, 8, 3), dim3(256), 0, stream>>>(xb, cb, wT, ao, qkv, bo, out, 0);
    flash_attn<<<dim3(16, 16, 2), dim3(256), 0, stream>>>(qkv, qkv + 4194304, qkv + 8388608, ao);
    gemm128<<<dim3(32, 8, 1), dim3(256), 0, stream>>>(xb, cb, wT, ao, qkv, bo, out, 3);
}